// Round 7
// baseline (776.107 us; speedup 1.0000x reference)
//
#include <hip/hip_runtime.h>
#include <math.h>

#define B 2
#define S 1024
#define H 8
#define DIM 128
#define NCMP 63      // (1024-32)/16+1
#define NSLC 61      // (1024-64)/16+1
#define QB 64        // BLOCK_Q
#define NQB (S/QB)   // 16
#define WIN 128
#define SCALE  0.08838834764831845f   // 128^-0.5
#define RSCALE 11.313708498984761f    // 128^+0.5  (cmp branch divides by scale)

typedef float v2f __attribute__((ext_vector_type(2)));

// ---------------- kernel 1: compressed K/V (vectorized) ----------------
__global__ __launch_bounds__(64) void cmp_kv_kernel(
    const float* __restrict__ k, const float* __restrict__ v,
    const float* __restrict__ wck, const float* __restrict__ bck,
    const float* __restrict__ wcv, const float* __restrict__ bcv,
    float* __restrict__ Kc, float* __restrict__ Vc)
{
  const int d0 = threadIdx.x * 2;
  const int n = blockIdx.x, h = blockIdx.y, b = blockIdx.z;
  const size_t rs = (size_t)H * DIM;
  const float* kp = k + (size_t)b*S*rs + (size_t)(n*16)*rs + (size_t)h*DIM + d0;
  const float* vp = v + (kp - k);
  v2f sk = {0.f, 0.f}, sv = {0.f, 0.f};
  #pragma unroll
  for (int l = 0; l < 32; ++l) {
    v2f kk = *(const v2f*)(kp + (size_t)l*rs);
    v2f vv = *(const v2f*)(vp + (size_t)l*rs);
    sk += kk * wck[l];
    sv += vv * wcv[l];
  }
  sk += bck[0];
  sv += bcv[0];
  size_t oi = ((size_t)(b*H + h)*NCMP + n)*(size_t)DIM + d0;
  *(v2f*)(Kc + oi) = sk;
  *(v2f*)(Vc + oi) = sv;
}

// ---------------- wave reductions (wave64) ----------------
__device__ __forceinline__ float wave_max(float x) {
  #pragma unroll
  for (int off = 32; off > 0; off >>= 1) x = fmaxf(x, __shfl_xor(x, off));
  return x;
}
__device__ __forceinline__ float wave_sum(float x) {
  #pragma unroll
  for (int off = 32; off > 0; off >>= 1) x += __shfl_xor(x, off);
  return x;
}

// QK: lane owns key j (row of swizzled k4), 4 queries broadcast from q_lds.
__device__ __forceinline__ void qk4(const float (*q_lds)[DIM], const float4 (*k4)[32],
                                    int q0, int lane, float sc[4]) {
  v2f a0[4], a1[4];
  #pragma unroll
  for (int qq = 0; qq < 4; ++qq) { a0[qq] = (v2f){0.f,0.f}; a1[qq] = (v2f){0.f,0.f}; }
  const int jsw = lane & 7;
  #pragma unroll
  for (int g = 0; g < 32; ++g) {
    float4 kk = k4[lane][g ^ jsw];
    v2f k01 = {kk.x, kk.y};
    v2f k23 = {kk.z, kk.w};
    #pragma unroll
    for (int qq = 0; qq < 4; ++qq) {
      float4 qv = *(const float4*)&q_lds[q0 + qq][g << 2];
      v2f q01 = {qv.x, qv.y};
      v2f q23 = {qv.z, qv.w};
      a0[qq] += q01 * k01;
      a1[qq] += q23 * k23;
    }
  }
  #pragma unroll
  for (int qq = 0; qq < 4; ++qq)
    sc[qq] = (a0[qq].x + a0[qq].y) + (a1[qq].x + a1[qq].y);
}

// PV: lane owns d-pair; p broadcast (float4 = 4 queries) from transposed p_lds;
// v read directly from global (wave-uniform row -> coalesced, L1/L2 resident).
__device__ __forceinline__ void pv_global(const float* __restrict__ vbase, size_t rowstride,
                                          int row0, int rowmax,
                                          const float (*p_lds)[64], int g0, int lane,
                                          v2f acc[4]) {
  const int d0 = lane * 2;
  #pragma unroll 8
  for (int j = 0; j < 64; ++j) {
    float4 pv = *(const float4*)&p_lds[j][((g0 ^ (j & 15)) << 2)];
    int row = row0 + j;
    row = row < 0 ? 0 : (row > rowmax ? rowmax : row);
    v2f vv = *(const v2f*)(vbase + (size_t)row*rowstride + d0);
    acc[0] += vv * pv.x;
    acc[1] += vv * pv.y;
    acc[2] += vv * pv.z;
    acc[3] += vv * pv.w;
  }
}

// ---------------- kernel 2: mega (one block per b,h,q-block) ----------------
__global__ __launch_bounds__(1024) void nsa_mega(
    const float* __restrict__ qg, const float* __restrict__ kg, const float* __restrict__ vg,
    const float* __restrict__ Kc, const float* __restrict__ Vc,
    const float* __restrict__ wgate, const float* __restrict__ bgate,
    float* __restrict__ outg)
{
  __shared__ __align__(16) float q_lds[QB][DIM];   // 32 KB, broadcast-read only
  __shared__ float4 kb[3][64][32];                 // 96 KB, XOR-swizzled keys, 3 buffers
  __shared__ __align__(16) float p_lds[64][64];    // 16 KB, [key][query], group-swizzled
  __shared__ float S_col[64];
  __shared__ __align__(16) float gw[3][DIM];
  __shared__ int   sel[2];

  const int tid  = threadIdx.x;
  const int lane = tid & 63;
  const int wid  = tid >> 6;           // 0..15
  const int qb = blockIdx.x, h = blockIdx.y, b = blockIdx.z;
  const int bh = b*H + h;
  const int q0  = wid * 4;
  const int iq0 = qb*QB + q0;
  const size_t rs = (size_t)H * DIM;
  const float* qg_bh = qg + (size_t)b*S*rs + (size_t)h*DIM;
  const float* kg_bh = kg + (size_t)b*S*rs + (size_t)h*DIM;
  const float* vg_bh = vg + (size_t)b*S*rs + (size_t)h*DIM;
  const float* KcBH  = Kc + (size_t)bh*NCMP*DIM;
  const float* VcBH  = Vc + (size_t)bh*NCMP*DIM;

  const int ju0  = tid >> 5;           // 0..31 (staging row, unit 0; unit 1 = +32)
  const int gu   = tid & 31;           // float4 group 0..31
  const int jsw0 = ju0 & 7;            // == (ju0+32)&7

  // ---- P0: stage q, gate weights, cmp-K -> kb2, window t0 K -> kb0 ----
  {
    int qrow = qb*QB + ju0;
    *(float4*)&q_lds[ju0][gu*4]    = *(const float4*)(qg_bh + (size_t)qrow*rs + gu*4);
    *(float4*)&q_lds[ju0+32][gu*4] = *(const float4*)(qg_bh + (size_t)(qrow+32)*rs + gu*4);
    if (tid < 384) gw[tid >> 7][tid & 127] = wgate[tid];

    float4 c0 = *(const float4*)(KcBH + (size_t)ju0*DIM + gu*4);
    float4 c1 = (ju0+32 < NCMP) ? *(const float4*)(KcBH + (size_t)(ju0+32)*DIM + gu*4)
                                : make_float4(0.f,0.f,0.f,0.f);
    kb[2][ju0][gu ^ jsw0]    = c0;
    kb[2][ju0+32][gu ^ jsw0] = c1;

    int row0 = qb*QB - WIN;            // window tile 0
    int r = row0 + ju0;
    float4 w0 = (r >= 0 && r < S) ? *(const float4*)(kg_bh + (size_t)r*rs + gu*4)
                                  : make_float4(0.f,0.f,0.f,0.f);
    r = row0 + ju0 + 32;
    float4 w1 = (r >= 0 && r < S) ? *(const float4*)(kg_bh + (size_t)r*rs + gu*4)
                                  : make_float4(0.f,0.f,0.f,0.f);
    kb[0][ju0][gu ^ jsw0]    = w0;
    kb[0][ju0+32][gu ^ jsw0] = w1;
  }
  __syncthreads();   // b0

  // p_lds column-group swizzle: row = key lane, float4 group = wid ^ (row&15).
  // Bijective per row (XOR on 0..15); write = one b128/lane at the 8-lane/bank-group
  // floor (conflict-free); read side is wave-uniform broadcast.
  const int pcolg = ((wid ^ (lane & 15)) << 2);

  // ---- cmp branch: QK + softmax (with max; logits std ~128) + PV ----
  v2f accC[4];
  #pragma unroll
  for (int qq = 0; qq < 4; ++qq) accC[qq] = (v2f){0.f,0.f};
  {
    float sc[4];
    qk4(q_lds, kb[2], q0, lane, sc);
    float4 p4;
    #pragma unroll
    for (int qq = 0; qq < 4; ++qq) {
      float svv = (lane < NCMP) ? sc[qq]*RSCALE : -INFINITY;
      float m = wave_max(svv);
      float p = __expf(svv - m);
      float l = wave_sum(p);
      ((float*)&p4)[qq] = p * (1.f/l);              // normalized (needed for top-k)
    }
    *(float4*)&p_lds[lane][pcolg] = p4;
    pv_global(VcBH, DIM, 0, NCMP-1, p_lds, wid, lane, accC);
  }
  __syncthreads();   // b1 (selection needs all waves' p columns)

  // ---- selection: group-sum P_cmp -> M-map -> top-2 (wave 0) ----
  if (wid == 0) {
    float ssum = 0.f;
    const int gx = lane & 15;
    #pragma unroll
    for (int g = 0; g < 16; ++g) {
      float4 t4 = *(const float4*)&p_lds[lane][(g ^ gx) << 2];
      ssum += (t4.x + t4.y) + (t4.z + t4.w);
    }
    S_col[lane] = ssum;
    asm volatile("s_waitcnt lgkmcnt(0)" ::: "memory");
    float val = -INFINITY;
    if (lane < NSLC) {
      const float wts[5] = {1.f, 2.f, 2.f, 2.f, 1.f};
      float a = 0.f;
      #pragma unroll
      for (int o = 0; o < 5; ++o) {
        int i = 4*lane - o;
        if (i >= 0 && i < NCMP) a += wts[o] * S_col[i];
      }
      val = a;
    }
    float v1 = val; int i1 = lane;
    #pragma unroll
    for (int off = 32; off > 0; off >>= 1) {
      float ov = __shfl_xor(v1, off); int oi = __shfl_xor(i1, off);
      if (ov > v1 || (ov == v1 && oi < i1)) { v1 = ov; i1 = oi; }
    }
    int s0i = i1;
    float v2 = (lane == s0i) ? -INFINITY : val; int i2 = lane;
    #pragma unroll
    for (int off = 32; off > 0; off >>= 1) {
      float ov = __shfl_xor(v2, off); int oi = __shfl_xor(i2, off);
      if (ov > v2 || (ov == v2 && oi < i2)) { v2 = ov; i2 = oi; }
    }
    if (lane == 0) { sel[0] = s0i; sel[1] = i2; }
  }
  __syncthreads();   // b2

  // ---- stage selected blocks: A -> kb1, B -> kb2; prefetch window t1 ----
  const int rowA = sel[0] * 16;
  const int rowB = sel[1] * 16;
  {
    float4 a0 = *(const float4*)(kg_bh + (size_t)(rowA+ju0)*rs + gu*4);
    float4 a1 = *(const float4*)(kg_bh + (size_t)(rowA+ju0+32)*rs + gu*4);
    kb[1][ju0][gu ^ jsw0]    = a0;
    kb[1][ju0+32][gu ^ jsw0] = a1;
    float4 b0_ = *(const float4*)(kg_bh + (size_t)(rowB+ju0)*rs + gu*4);
    float4 b1_ = *(const float4*)(kg_bh + (size_t)(rowB+ju0+32)*rs + gu*4);
    kb[2][ju0][gu ^ jsw0]    = b0_;
    kb[2][ju0+32][gu ^ jsw0] = b1_;
  }
  float4 wA, wB;   // register prefetch for window tile t+1
  {
    int row0 = qb*QB - WIN + 64;       // tile 1
    int r = row0 + ju0;
    wA = (r >= 0 && r < S) ? *(const float4*)(kg_bh + (size_t)r*rs + gu*4)
                           : make_float4(0.f,0.f,0.f,0.f);
    r = row0 + ju0 + 32;
    wB = (r >= 0 && r < S) ? *(const float4*)(kg_bh + (size_t)r*rs + gu*4)
                           : make_float4(0.f,0.f,0.f,0.f);
  }
  __syncthreads();   // b3

  // ---- selected branch: deferred-norm softmax (logits ~N(0,1), no max needed) ----
  v2f accS[4];
  float lsumS[4] = {0.f,0.f,0.f,0.f};
  #pragma unroll
  for (int qq = 0; qq < 4; ++qq) accS[qq] = (v2f){0.f,0.f};
  {
    float scA[4], scB[4];
    qk4(q_lds, kb[1], q0, lane, scA);
    qk4(q_lds, kb[2], q0, lane, scB);
    float4 p4;
    #pragma unroll
    for (int qq = 0; qq < 4; ++qq) {
      float pA = __expf(scA[qq]*SCALE);
      ((float*)&p4)[qq] = pA;
      lsumS[qq] += pA;
    }
    *(float4*)&p_lds[lane][pcolg] = p4;
    pv_global(vg_bh, rs, rowA, S-1, p_lds, wid, lane, accS);
    #pragma unroll
    for (int qq = 0; qq < 4; ++qq) {
      float pB = __expf(scB[qq]*SCALE);
      ((float*)&p4)[qq] = pB;
      lsumS[qq] += pB;
    }
    *(float4*)&p_lds[lane][pcolg] = p4;
    pv_global(vg_bh, rs, rowB, S-1, p_lds, wid, lane, accS);
  }
  __syncthreads();   // b4 (kb1/kb2 free for window reuse)

  // ---- window branch: 6 tiles, deferred-norm, triple-buffered k ----
  v2f accW[4];
  float lsumW[4] = {0.f,0.f,0.f,0.f};
  #pragma unroll
  for (int qq = 0; qq < 4; ++qq) accW[qq] = (v2f){0.f,0.f};

  for (int t = 0; t < 6; ++t) {
    int row0 = qb*QB - WIN + t*64;
    if (t < 5) {                        // write prefetched tile t+1
      int nb = (t+1) % 3;
      kb[nb][ju0][gu ^ jsw0]    = wA;
      kb[nb][ju0+32][gu ^ jsw0] = wB;
    }
    if (t < 4) {                        // issue loads for tile t+2
      int r0n = qb*QB - WIN + (t+2)*64;
      int r = r0n + ju0;
      wA = (r >= 0 && r < S) ? *(const float4*)(kg_bh + (size_t)r*rs + gu*4)
                             : make_float4(0.f,0.f,0.f,0.f);
      r = r0n + ju0 + 32;
      wB = (r >= 0 && r < S) ? *(const float4*)(kg_bh + (size_t)r*rs + gu*4)
                             : make_float4(0.f,0.f,0.f,0.f);
    }
    float sc[4];
    qk4(q_lds, kb[t % 3], q0, lane, sc);
    int jabs = row0 + lane;
    bool jin = (jabs >= 0) & (jabs < S);
    float4 p4;
    #pragma unroll
    for (int qq = 0; qq < 4; ++qq) {
      int ig = iq0 + qq;
      bool valid = jin & (jabs >= ig - WIN) & (jabs <= ig + WIN);
      float pj = valid ? __expf(sc[qq]*SCALE) : 0.f;
      ((float*)&p4)[qq] = pj;
      lsumW[qq] += pj;
    }
    *(float4*)&p_lds[lane][pcolg] = p4;
    pv_global(vg_bh, rs, row0, S-1, p_lds, wid, lane, accW);
    if (t < 5) __syncthreads();
  }

  // ---- normalize, gate, combine, write ----
  float lS[4], lW[4];
  #pragma unroll
  for (int qq = 0; qq < 4; ++qq) { lS[qq] = wave_sum(lsumS[qq]); lW[qq] = wave_sum(lsumW[qq]); }

  const int d0 = lane * 2;
  #pragma unroll
  for (int qq = 0; qq < 4; ++qq) {
    int qi = q0 + qq;
    v2f qv = *(const v2f*)&q_lds[qi][d0];
    float g_[3];
    #pragma unroll
    for (int c = 0; c < 3; ++c) {
      v2f gwv = *(const v2f*)&gw[c][d0];
      float part = qv.x*gwv.x + qv.y*gwv.y;
      part = wave_sum(part);
      g_[c] = 1.f / (1.f + __expf(-(part + bgate[c])));
    }
    v2f o = accC[qq]*g_[0] + accS[qq]*(g_[1]/lS[qq]) + accW[qq]*(g_[2]/lW[qq]);
    size_t oi = (size_t)b*S*rs + (size_t)(iq0+qq)*rs + (size_t)h*DIM + d0;
    *(v2f*)(outg + oi) = o;
  }
}

extern "C" void kernel_launch(void* const* d_in, const int* in_sizes, int n_in,
                              void* d_out, int out_size, void* d_ws, size_t ws_size,
                              hipStream_t stream) {
  const float* q   = (const float*)d_in[0];
  const float* k   = (const float*)d_in[1];
  const float* v   = (const float*)d_in[2];
  const float* wck = (const float*)d_in[3];
  const float* bck = (const float*)d_in[4];
  const float* wcv = (const float*)d_in[5];
  const float* bcv = (const float*)d_in[6];
  const float* wg  = (const float*)d_in[7];
  const float* bg  = (const float*)d_in[8];
  float* out = (float*)d_out;

  float* Kc = (float*)d_ws;
  float* Vc = Kc + (size_t)B*H*NCMP*DIM;

  cmp_kv_kernel<<<dim3(NCMP, H, B), 64, 0, stream>>>(k, v, wck, bck, wcv, bcv, Kc, Vc);
  nsa_mega<<<dim3(NQB, H, B), 1024, 0, stream>>>(q, k, v, Kc, Vc, wg, bg, out);
}

// Round 8
// 462.676 us; speedup vs baseline: 1.6774x; 1.6774x over previous
//
#include <hip/hip_runtime.h>
#include <math.h>

#define B 2
#define S 1024
#define H 8
#define DIM 128
#define NCMP 63      // (1024-32)/16+1
#define NSLC 61      // (1024-64)/16+1
#define QB 64        // BLOCK_Q
#define NQB (S/QB)   // 16
#define WIN 128
#define SCALE  0.08838834764831845f   // 128^-0.5
#define RSCALE 11.313708498984761f    // 128^+0.5  (cmp branch divides by scale)

typedef float v2f __attribute__((ext_vector_type(2)));

// ---------------- kernel 1: compressed K/V ----------------
__global__ __launch_bounds__(64) void cmp_kv_kernel(
    const float* __restrict__ k, const float* __restrict__ v,
    const float* __restrict__ wck, const float* __restrict__ bck,
    const float* __restrict__ wcv, const float* __restrict__ bcv,
    float* __restrict__ Kc, float* __restrict__ Vc)
{
  const int d0 = threadIdx.x * 2;
  const int n = blockIdx.x, h = blockIdx.y, b = blockIdx.z;
  const size_t rs = (size_t)H * DIM;
  const float* kp = k + (size_t)b*S*rs + (size_t)(n*16)*rs + (size_t)h*DIM + d0;
  const float* vp = v + (kp - k);
  v2f sk = {0.f, 0.f}, sv = {0.f, 0.f};
  #pragma unroll
  for (int l = 0; l < 32; ++l) {
    v2f kk = *(const v2f*)(kp + (size_t)l*rs);
    v2f vv = *(const v2f*)(vp + (size_t)l*rs);
    sk += kk * wck[l];
    sv += vv * wcv[l];
  }
  sk += bck[0];
  sv += bcv[0];
  size_t oi = ((size_t)(b*H + h)*NCMP + n)*(size_t)DIM + d0;
  *(v2f*)(Kc + oi) = sk;
  *(v2f*)(Vc + oi) = sv;
}

// ---------------- wave reductions (wave64) ----------------
__device__ __forceinline__ float wave_max(float x) {
  #pragma unroll
  for (int off = 32; off > 0; off >>= 1) x = fmaxf(x, __shfl_xor(x, off));
  return x;
}
__device__ __forceinline__ float wave_sum(float x) {
  #pragma unroll
  for (int off = 32; off > 0; off >>= 1) x += __shfl_xor(x, off);
  return x;
}
__device__ __forceinline__ int clampS(int r) { return r < 0 ? 0 : (r > S-1 ? S-1 : r); }

// QK: lane owns key j; 4 queries broadcast from q_lds. Named accumulators, no arrays.
__device__ __forceinline__ float4 qk4(const float (*q_lds)[DIM], const float4 (*k4)[32],
                                      int q0, int lane) {
  v2f a0x={0,0}, a0y={0,0}, a1x={0,0}, a1y={0,0};
  v2f a2x={0,0}, a2y={0,0}, a3x={0,0}, a3y={0,0};
  const int jsw = lane & 7;
  #pragma unroll
  for (int g = 0; g < 32; ++g) {
    float4 kk = k4[lane][g ^ jsw];
    v2f k01 = {kk.x, kk.y}, k23 = {kk.z, kk.w};
    float4 qa = *(const float4*)&q_lds[q0+0][g<<2];
    float4 qb = *(const float4*)&q_lds[q0+1][g<<2];
    float4 qc = *(const float4*)&q_lds[q0+2][g<<2];
    float4 qd = *(const float4*)&q_lds[q0+3][g<<2];
    a0x += (v2f){qa.x,qa.y}*k01; a0y += (v2f){qa.z,qa.w}*k23;
    a1x += (v2f){qb.x,qb.y}*k01; a1y += (v2f){qb.z,qb.w}*k23;
    a2x += (v2f){qc.x,qc.y}*k01; a2y += (v2f){qc.z,qc.w}*k23;
    a3x += (v2f){qd.x,qd.y}*k01; a3y += (v2f){qd.z,qd.w}*k23;
  }
  float4 r;
  r.x = (a0x.x+a0x.y)+(a0y.x+a0y.y);
  r.y = (a1x.x+a1x.y)+(a1y.x+a1y.y);
  r.z = (a2x.x+a2x.y)+(a2y.x+a2y.y);
  r.w = (a3x.x+a3x.y)+(a3y.x+a3y.y);
  return r;
}

// PV: lane owns d-pair; p broadcast (float4 = 4 queries); v from LDS (conflict-floor b64).
__device__ __forceinline__ void pv_lds(const float (*v_lds)[DIM],
                                       const float (*p_lds)[64], int g0, int lane,
                                       v2f acc[4]) {
  const int d0 = lane * 2;
  #pragma unroll 8
  for (int j = 0; j < 64; ++j) {
    float4 pv = *(const float4*)&p_lds[j][((g0 ^ (j & 15)) << 2)];
    v2f vv = *(const v2f*)&v_lds[j][d0];
    acc[0] += vv * pv.x;
    acc[1] += vv * pv.y;
    acc[2] += vv * pv.z;
    acc[3] += vv * pv.w;
  }
}

// ---------------- kernel 2: mega ----------------
__global__ __launch_bounds__(1024, 4) void nsa_mega(
    const float* __restrict__ qg, const float* __restrict__ kg, const float* __restrict__ vg,
    const float* __restrict__ Kc, const float* __restrict__ Vc,
    const float* __restrict__ wgate, const float* __restrict__ bgate,
    float* __restrict__ outg)
{
  __shared__ __align__(16) float q_lds[QB][DIM];   // 32 KB
  __shared__ float4 kb[2][64][32];                 // 64 KB, swizzled keys, double-buffered
  __shared__ __align__(16) float v_lds[64][DIM];   // 32 KB, staged just-in-time
  __shared__ __align__(16) float p_lds[64][64];    // 16 KB, [key][query]
  __shared__ float S_col[64];
  __shared__ __align__(16) float gw[3][DIM];
  __shared__ int sel[2];                           // total ~146 KB -> 1 block/CU

  const int tid  = threadIdx.x;
  const int lane = tid & 63;
  const int wid  = tid >> 6;
  const int qb = blockIdx.x, h = blockIdx.y, b = blockIdx.z;
  const int bh = b*H + h;
  const int q0  = wid * 4;
  const int iq0 = qb*QB + q0;
  const size_t rs = (size_t)H * DIM;
  const float* qg_bh = qg + (size_t)b*S*rs + (size_t)h*DIM;
  const float* kg_bh = kg + (size_t)b*S*rs + (size_t)h*DIM;
  const float* vg_bh = vg + (size_t)b*S*rs + (size_t)h*DIM;
  const float* KcBH  = Kc + (size_t)bh*NCMP*DIM;
  const float* VcBH  = Vc + (size_t)bh*NCMP*DIM;

  const int ju0  = tid >> 5;           // staging row (and row+32)
  const int gu   = tid & 31;           // float4 column
  const int jsw0 = ju0 & 7;            // == (ju0+32)&7

  // ---- P0: q, gate weights, cmp K->kb0, cmp V->v_lds ----
  {
    int qrow = qb*QB + ju0;
    *(float4*)&q_lds[ju0][gu*4]    = *(const float4*)(qg_bh + (size_t)qrow*rs + gu*4);
    *(float4*)&q_lds[ju0+32][gu*4] = *(const float4*)(qg_bh + (size_t)(qrow+32)*rs + gu*4);
    if (tid < 384) gw[tid >> 7][tid & 127] = wgate[tid];
    int rc1 = (ju0+32 < NCMP) ? ju0+32 : NCMP-1;   // row 63 -> dup of 62 (masked later)
    kb[0][ju0][gu ^ jsw0]    = *(const float4*)(KcBH + (size_t)ju0*DIM + gu*4);
    kb[0][ju0+32][gu ^ jsw0] = *(const float4*)(KcBH + (size_t)rc1*DIM + gu*4);
    *(float4*)&v_lds[ju0][gu*4]    = *(const float4*)(VcBH + (size_t)ju0*DIM + gu*4);
    *(float4*)&v_lds[ju0+32][gu*4] = *(const float4*)(VcBH + (size_t)rc1*DIM + gu*4);
  }
  __syncthreads();   // b0

  const int pcolg = ((wid ^ (lane & 15)) << 2);

  // ---- cmp branch (kept fp32, max-subtracted: logits std ~128) ----
  v2f accC[4] = {v2f{0,0},v2f{0,0},v2f{0,0},v2f{0,0}};
  {
    float4 sc = qk4(q_lds, kb[0], q0, lane);
    float4 p4;
    { float s = (lane<NCMP)? sc.x*RSCALE : -INFINITY; float m=wave_max(s);
      float p=__expf(s-m); p4.x = p*(1.f/wave_sum(p)); }
    { float s = (lane<NCMP)? sc.y*RSCALE : -INFINITY; float m=wave_max(s);
      float p=__expf(s-m); p4.y = p*(1.f/wave_sum(p)); }
    { float s = (lane<NCMP)? sc.z*RSCALE : -INFINITY; float m=wave_max(s);
      float p=__expf(s-m); p4.z = p*(1.f/wave_sum(p)); }
    { float s = (lane<NCMP)? sc.w*RSCALE : -INFINITY; float m=wave_max(s);
      float p=__expf(s-m); p4.w = p*(1.f/wave_sum(p)); }
    *(float4*)&p_lds[lane][pcolg] = p4;
    pv_lds(v_lds, p_lds, wid, lane, accC);
  }
  __syncthreads();   // b1

  // ---- selection: group-sum P_cmp -> M-map -> top-2 (wave 0) ----
  if (wid == 0) {
    float ssum = 0.f;
    const int gx = lane & 15;
    #pragma unroll
    for (int g = 0; g < 16; ++g) {
      float4 t4 = *(const float4*)&p_lds[lane][(g ^ gx) << 2];
      ssum += (t4.x + t4.y) + (t4.z + t4.w);
    }
    S_col[lane] = ssum;
    asm volatile("s_waitcnt lgkmcnt(0)" ::: "memory");
    float val = -INFINITY;
    if (lane < NSLC) {
      const float wts[5] = {1.f, 2.f, 2.f, 2.f, 1.f};
      float a = 0.f;
      #pragma unroll
      for (int o = 0; o < 5; ++o) {
        int i = 4*lane - o;
        if (i >= 0 && i < NCMP) a += wts[o] * S_col[i];
      }
      val = a;
    }
    float v1 = val; int i1 = lane;
    #pragma unroll
    for (int off = 32; off > 0; off >>= 1) {
      float ov = __shfl_xor(v1, off); int oi = __shfl_xor(i1, off);
      if (ov > v1 || (ov == v1 && oi < i1)) { v1 = ov; i1 = oi; }
    }
    int s0i = i1;
    float v2 = (lane == s0i) ? -INFINITY : val; int i2 = lane;
    #pragma unroll
    for (int off = 32; off > 0; off >>= 1) {
      float ov = __shfl_xor(v2, off); int oi = __shfl_xor(i2, off);
      if (ov > v2 || (ov == v2 && oi < i2)) { v2 = ov; i2 = oi; }
    }
    if (lane == 0) { sel[0] = s0i; sel[1] = i2; }
  }
  __syncthreads();   // b2

  // ---- stage slc: kb0<-K[A], kb1<-K[B], v_lds<-V[A]  (rows <= 1023, no clamp) ----
  const int rowA = sel[0] * 16;
  const int rowB = sel[1] * 16;
  {
    kb[0][ju0][gu ^ jsw0]    = *(const float4*)(kg_bh + (size_t)(rowA+ju0)*rs + gu*4);
    kb[0][ju0+32][gu ^ jsw0] = *(const float4*)(kg_bh + (size_t)(rowA+ju0+32)*rs + gu*4);
    kb[1][ju0][gu ^ jsw0]    = *(const float4*)(kg_bh + (size_t)(rowB+ju0)*rs + gu*4);
    kb[1][ju0+32][gu ^ jsw0] = *(const float4*)(kg_bh + (size_t)(rowB+ju0+32)*rs + gu*4);
    *(float4*)&v_lds[ju0][gu*4]    = *(const float4*)(vg_bh + (size_t)(rowA+ju0)*rs + gu*4);
    *(float4*)&v_lds[ju0+32][gu*4] = *(const float4*)(vg_bh + (size_t)(rowA+ju0+32)*rs + gu*4);
  }
  __syncthreads();   // b3

  // ---- selected branch: deferred-norm softmax over 128 keys ----
  v2f accS[4] = {v2f{0,0},v2f{0,0},v2f{0,0},v2f{0,0}};
  float4 scA = qk4(q_lds, kb[0], q0, lane);
  float4 scB = qk4(q_lds, kb[1], q0, lane);
  float4 pA, pB;
  pA.x = __expf(scA.x*SCALE); pA.y = __expf(scA.y*SCALE);
  pA.z = __expf(scA.z*SCALE); pA.w = __expf(scA.w*SCALE);
  pB.x = __expf(scB.x*SCALE); pB.y = __expf(scB.y*SCALE);
  pB.z = __expf(scB.z*SCALE); pB.w = __expf(scB.w*SCALE);
  float4 lsumS4;
  lsumS4.x = pA.x+pB.x; lsumS4.y = pA.y+pB.y;
  lsumS4.z = pA.z+pB.z; lsumS4.w = pA.w+pB.w;
  *(float4*)&p_lds[lane][pcolg] = pA;
  pv_lds(v_lds, p_lds, wid, lane, accS);        // V[rowA]
  __syncthreads(); // b4
  {  // restage: v_lds<-V[B]; kb0<-K(win t0)
    *(float4*)&v_lds[ju0][gu*4]    = *(const float4*)(vg_bh + (size_t)(rowB+ju0)*rs + gu*4);
    *(float4*)&v_lds[ju0+32][gu*4] = *(const float4*)(vg_bh + (size_t)(rowB+ju0+32)*rs + gu*4);
    int w0 = qb*QB - WIN;
    kb[0][ju0][gu ^ jsw0]    = *(const float4*)(kg_bh + (size_t)clampS(w0+ju0)*rs + gu*4);
    kb[0][ju0+32][gu ^ jsw0] = *(const float4*)(kg_bh + (size_t)clampS(w0+ju0+32)*rs + gu*4);
  }
  __syncthreads(); // b5
  *(float4*)&p_lds[lane][pcolg] = pB;
  pv_lds(v_lds, p_lds, wid, lane, accS);        // V[rowB]
  __syncthreads(); // b6
  {  // stage: v_lds<-V(w0); kb1<-K(w1)
    int w0 = qb*QB - WIN, w1 = w0 + 64;
    *(float4*)&v_lds[ju0][gu*4]    = *(const float4*)(vg_bh + (size_t)clampS(w0+ju0)*rs + gu*4);
    *(float4*)&v_lds[ju0+32][gu*4] = *(const float4*)(vg_bh + (size_t)clampS(w0+ju0+32)*rs + gu*4);
    kb[1][ju0][gu ^ jsw0]    = *(const float4*)(kg_bh + (size_t)clampS(w1+ju0)*rs + gu*4);
    kb[1][ju0+32][gu ^ jsw0] = *(const float4*)(kg_bh + (size_t)clampS(w1+ju0+32)*rs + gu*4);
  }
  __syncthreads(); // b7

  // ---- window branch: 6 tiles, k double-buffered, v just-in-time ----
  v2f accW[4] = {v2f{0,0},v2f{0,0},v2f{0,0},v2f{0,0}};
  float4 lsumW4 = {0.f,0.f,0.f,0.f};
  for (int t = 0; t < 6; ++t) {
    float4 sc = qk4(q_lds, kb[t & 1], q0, lane);
    int row0 = qb*QB - WIN + t*64;
    int jabs = row0 + lane;
    bool jin = (jabs >= 0) & (jabs < S);
    float4 p4;
    { bool ok = jin & (jabs >= iq0+0-WIN) & (jabs <= iq0+0+WIN); p4.x = ok ? __expf(sc.x*SCALE) : 0.f; }
    { bool ok = jin & (jabs >= iq0+1-WIN) & (jabs <= iq0+1+WIN); p4.y = ok ? __expf(sc.y*SCALE) : 0.f; }
    { bool ok = jin & (jabs >= iq0+2-WIN) & (jabs <= iq0+2+WIN); p4.z = ok ? __expf(sc.z*SCALE) : 0.f; }
    { bool ok = jin & (jabs >= iq0+3-WIN) & (jabs <= iq0+3+WIN); p4.w = ok ? __expf(sc.w*SCALE) : 0.f; }
    lsumW4.x += p4.x; lsumW4.y += p4.y; lsumW4.z += p4.z; lsumW4.w += p4.w;
    *(float4*)&p_lds[lane][pcolg] = p4;
    pv_lds(v_lds, p_lds, wid, lane, accW);
    if (t < 5) {
      __syncthreads();
      int wn = row0 + 64;                       // v tile t+1
      *(float4*)&v_lds[ju0][gu*4]    = *(const float4*)(vg_bh + (size_t)clampS(wn+ju0)*rs + gu*4);
      *(float4*)&v_lds[ju0+32][gu*4] = *(const float4*)(vg_bh + (size_t)clampS(wn+ju0+32)*rs + gu*4);
      if (t < 4) {
        int wk = row0 + 128;                    // k tile t+2 -> kb[t&1]
        kb[t & 1][ju0][gu ^ jsw0]    = *(const float4*)(kg_bh + (size_t)clampS(wk+ju0)*rs + gu*4);
        kb[t & 1][ju0+32][gu ^ jsw0] = *(const float4*)(kg_bh + (size_t)clampS(wk+ju0+32)*rs + gu*4);
      }
      __syncthreads();
    }
  }

  // ---- normalize, gate, combine, write ----
  float lS[4] = { wave_sum(lsumS4.x), wave_sum(lsumS4.y), wave_sum(lsumS4.z), wave_sum(lsumS4.w) };
  float lW[4] = { wave_sum(lsumW4.x), wave_sum(lsumW4.y), wave_sum(lsumW4.z), wave_sum(lsumW4.w) };

  const int d0 = lane * 2;
  #pragma unroll
  for (int qq = 0; qq < 4; ++qq) {
    int qi = q0 + qq;
    v2f qv = *(const v2f*)&q_lds[qi][d0];
    float g_[3];
    #pragma unroll
    for (int c = 0; c < 3; ++c) {
      v2f gwv = *(const v2f*)&gw[c][d0];
      float part = wave_sum(qv.x*gwv.x + qv.y*gwv.y);
      g_[c] = 1.f / (1.f + __expf(-(part + bgate[c])));
    }
    v2f o = accC[qq]*g_[0] + accS[qq]*(g_[1]/lS[qq]) + accW[qq]*(g_[2]/lW[qq]);
    size_t oi = (size_t)b*S*rs + (size_t)(iq0+qq)*rs + (size_t)h*DIM + d0;
    *(v2f*)(outg + oi) = o;
  }
}

extern "C" void kernel_launch(void* const* d_in, const int* in_sizes, int n_in,
                              void* d_out, int out_size, void* d_ws, size_t ws_size,
                              hipStream_t stream) {
  const float* q   = (const float*)d_in[0];
  const float* k   = (const float*)d_in[1];
  const float* v   = (const float*)d_in[2];
  const float* wck = (const float*)d_in[3];
  const float* bck = (const float*)d_in[4];
  const float* wcv = (const float*)d_in[5];
  const float* bcv = (const float*)d_in[6];
  const float* wg  = (const float*)d_in[7];
  const float* bg  = (const float*)d_in[8];
  float* out = (float*)d_out;

  float* Kc = (float*)d_ws;
  float* Vc = Kc + (size_t)B*H*NCMP*DIM;

  cmp_kv_kernel<<<dim3(NCMP, H, B), 64, 0, stream>>>(k, v, wck, bck, wcv, bcv, Kc, Vc);
  nsa_mega<<<dim3(NQB, H, B), 1024, 0, stream>>>(q, k, v, Kc, Vc, wg, bg, out);
}